// Round 1
// baseline (432.294 us; speedup 1.0000x reference)
//
#include <hip/hip_runtime.h>

#define N_NODES 50000
#define N_EDGES 800000
#define NB 196                        // buckets = ceil(50000/256)
#define P1_BLOCKS 256                 // hist/scatter blocks
#define EPB 3125                      // edges per block (256*3125 = 800000)
#define BH_SIZE (NB * P1_BLOCKS)      // 50176
#define GEMM_BLOCKS ((N_NODES + 63) / 64)     // 782
#define AGG_BLOCKS (N_NODES / 4)              // 12500

__device__ __forceinline__ float lrelu(float x) { return fmaxf(x, 0.2f * x); }
__device__ __forceinline__ float elu(float x) { return x > 0.f ? x : __expf(x) - 1.f; }

typedef float f32x2 __attribute__((ext_vector_type(2)));
typedef float f32x4v __attribute__((ext_vector_type(4)));
typedef short bf16x8 __attribute__((ext_vector_type(8)));

__device__ __forceinline__ unsigned f2bf_rn(float x) {
  unsigned u = __float_as_uint(x);
  return (u + 0x7fffu + ((u >> 16) & 1u)) >> 16;
}
__device__ __forceinline__ unsigned pack2bf(float a, float b) {
  return f2bf_rn(a) | (f2bf_rn(b) << 16);
}
__device__ __forceinline__ uint4 pack8bf(const float* v) {
  uint4 o;
  o.x = pack2bf(v[0], v[1]); o.y = pack2bf(v[2], v[3]);
  o.z = pack2bf(v[4], v[5]); o.w = pack2bf(v[6], v[7]);
  return o;
}

__device__ __forceinline__ int block_excl_scan(int v, int* total_out) {
  int lane = threadIdx.x & 63;
  int wid = threadIdx.x >> 6;
  int x = v;
#pragma unroll
  for (int off = 1; off < 64; off <<= 1) {
    int u = __shfl_up(x, off);
    if (lane >= off) x += u;
  }
  __shared__ int wsum[4];
  if (lane == 63) wsum[wid] = x;
  __syncthreads();
  int add = 0;
#pragma unroll
  for (int k = 0; k < 4; ++k)
    if (k < wid) add += wsum[k];
  if (total_out) *total_out = wsum[0] + wsum[1] + wsum[2] + wsum[3];
  return x + add - v;
}

// ---------------- dispatch 1: weight pack (blocks 0,1) || edge histogram (blocks 2..257) ----
// Packed layout for MFMA B-frags: Wpk[(ks*NF + f)*64 + lane] = 8 bf16 with
//   col = f*16 + (lane&15), k = ks*32 + (lane>>4)*8 + j   (j = 0..7)
// Layer1 cols: 0..127 = W1; 128+h = W1·atts1 (head h); 132+h = W1·attd1; 136..143 = 0.
// Layer2 cols: 0..63 = W2; 64 = W2·atts2; 65 = W2·attd2; 66..79 = 0.
__global__ __launch_bounds__(256) void setup_hist_kernel(
    const int* __restrict__ ei, int* __restrict__ bh,
    const float* __restrict__ W1, const float* __restrict__ atts1, const float* __restrict__ attd1,
    const float* __restrict__ W2, const float* __restrict__ atts2, const float* __restrict__ attd2,
    uint4* __restrict__ Wpk1, uint4* __restrict__ Wpk2) {
  __shared__ int cnt[NB];
  int bid = blockIdx.x;
  if (bid >= 2) {
    for (int t = threadIdx.x; t < NB; t += 256) cnt[t] = 0;
    __syncthreads();
    int start = (bid - 2) * EPB;
    for (int i = start + threadIdx.x; i < start + EPB; i += 256)
      atomicAdd(&cnt[ei[N_EDGES + i] >> 8], 1);
    __syncthreads();
    for (int t = threadIdx.x; t < NB; t += 256)
      bh[t * P1_BLOCKS + (bid - 2)] = cnt[t];
    return;
  }
  if (bid == 0) {
    for (int s = threadIdx.x; s < 4 * 9 * 64; s += 256) {
      int l = s & 63, sf = s >> 6;
      int f = sf % 9, ks = sf / 9;
      int colb = f * 16 + (l & 15);
      int kb = ks * 32 + ((l >> 4) << 3);
      float v[8];
      if (colb < 128) {
#pragma unroll
        for (int j = 0; j < 8; ++j) v[j] = W1[(kb + j) * 128 + colb];
      } else if (colb < 136) {
        int cc = colb - 128;
        const float* at = (cc < 4) ? atts1 : attd1;
        int h = cc & 3;
#pragma unroll
        for (int j = 0; j < 8; ++j) {
          float s2 = 0.f;
          for (int q = 0; q < 32; ++q) s2 += W1[(kb + j) * 128 + h * 32 + q] * at[h * 32 + q];
          v[j] = s2;
        }
      } else {
#pragma unroll
        for (int j = 0; j < 8; ++j) v[j] = 0.f;
      }
      Wpk1[s] = pack8bf(v);
    }
  } else {
    for (int s = threadIdx.x; s < 4 * 5 * 64; s += 256) {
      int l = s & 63, sf = s >> 6;
      int f = sf % 5, ks = sf / 5;
      int colb = f * 16 + (l & 15);
      int kb = ks * 32 + ((l >> 4) << 3);
      float v[8];
      if (colb < 64) {
#pragma unroll
        for (int j = 0; j < 8; ++j) v[j] = W2[(kb + j) * 64 + colb];
      } else if (colb < 66) {
        const float* at = (colb == 64) ? atts2 : attd2;
#pragma unroll
        for (int j = 0; j < 8; ++j) {
          float s2 = 0.f;
          for (int q = 0; q < 64; ++q) s2 += W2[(kb + j) * 64 + q] * at[q];
          v[j] = s2;
        }
      } else {
#pragma unroll
        for (int j = 0; j < 8; ++j) v[j] = 0.f;
      }
      Wpk2[s] = pack8bf(v);
    }
  }
}

// ---------------- MFMA GEMM body: 64 rows x (NF*16) cols, K=128, 4 waves ----------------
// A staged as bf16 in LDS, stride 136 (granule-bank-rotating: conflict-free b128 frag reads).
// B = packed Wpk staged linearly (lane-consecutive 16B reads, conflict-free).
// Last col-frag = attention dots (as | ad). Other frags packed to fp8 e4m3 via lane shuffles.
template <int NF, bool ABF16>
__device__ __forceinline__ void mfma_gemm_body(int bx, const void* __restrict__ Ap,
                                               const uint4* __restrict__ Wpk,
                                               unsigned* __restrict__ Yb,
                                               float* __restrict__ as_out, float* __restrict__ ad_out) {
  __shared__ unsigned short Xs[64 * 136];
  __shared__ uint4 Ws[NF * 256];
  int t = threadIdx.x;
  int rbase = bx * 64;
#pragma unroll
  for (int p = 0; p < NF; ++p) Ws[p * 256 + t] = Wpk[p * 256 + t];
  if constexpr (ABF16) {
    const uint4* A4 = (const uint4*)Ap;   // row = 128 bf16 = 16 uint4
#pragma unroll
    for (int p = 0; p < 4; ++p) {
      int i = p * 256 + t;
      int row = i >> 4, q = i & 15;
      int gr = rbase + row; if (gr > N_NODES - 1) gr = N_NODES - 1;
      *(uint4*)&Xs[row * 136 + q * 8] = A4[gr * 16 + q];
    }
  } else {
    const float4* A4 = (const float4*)Ap; // row = 32 float4
#pragma unroll
    for (int p = 0; p < 8; ++p) {
      int i = p * 256 + t;
      int row = i >> 5, q = i & 31;
      int gr = rbase + row; if (gr > N_NODES - 1) gr = N_NODES - 1;
      float4 v = A4[gr * 32 + q];
      *(uint2*)&Xs[row * 136 + q * 4] = make_uint2(pack2bf(v.x, v.y), pack2bf(v.z, v.w));
    }
  }
  __syncthreads();

  int l = t & 63, wv = t >> 6;
  int lc = l & 15, lk = l >> 4;
  f32x4v acc[NF];
#pragma unroll
  for (int f = 0; f < NF; ++f) acc[f] = (f32x4v){0.f, 0.f, 0.f, 0.f};
  const unsigned short* ap = &Xs[(wv * 16 + lc) * 136 + lk * 8];
#pragma unroll
  for (int ks = 0; ks < 4; ++ks) {
    bf16x8 a = *(const bf16x8*)(ap + ks * 32);
#pragma unroll
    for (int f = 0; f < NF; ++f) {
      bf16x8 b = *(const bf16x8*)&Ws[(ks * NF + f) * 64 + l];
      acc[f] = __builtin_amdgcn_mfma_f32_16x16x32_bf16(a, b, acc[f], 0, 0, 0);
    }
  }

  // C/D layout: col = f*16 + (lane&15), row = (lane>>4)*4 + reg
  constexpr int NCF = NF - 1;
#pragma unroll
  for (int reg = 0; reg < 4; ++reg) {
    int row = rbase + wv * 16 + lk * 4 + reg;
    bool rok = row < N_NODES;
    float av = acc[NCF][reg];
    if (rok) {
      if constexpr (NF == 9) {
        if (lc < 4) as_out[row * 4 + lc] = av;
        else if (lc < 8) ad_out[row * 4 + lc - 4] = av;
      } else {
        if (lc == 0) as_out[row] = av;
        else if (lc == 1) ad_out[row] = av;
      }
    }
    unsigned words[NCF];
#pragma unroll
    for (int f = 0; f < NCF; ++f) {
      float v = acc[f][reg];
      float n1 = __shfl_xor(v, 1);
      unsigned pk = (unsigned)__builtin_amdgcn_cvt_pk_fp8_f32(v, n1, 0, false);  // valid on even lanes
      unsigned pk2 = (unsigned)__shfl_xor((int)pk, 2);
      words[f] = (pk & 0xffffu) | (pk2 << 16);
    }
    if (rok && (lc & 3) == 0) {
#pragma unroll
      for (int f = 0; f < NCF; ++f)
        Yb[row * (NCF * 4) + f * 4 + (lc >> 2)] = words[f];
    }
  }
}

// ---------------- dispatch 2: gemm128 (blocks 0..781) || bh partial scan (782..977) --------
__global__ __launch_bounds__(256) void gemm128_scan_kernel(
    const float* __restrict__ x, const uint4* __restrict__ Wpk1,
    unsigned* __restrict__ h1b, float* __restrict__ as1, float* __restrict__ ad1,
    const int* __restrict__ bh, int* __restrict__ bhP, int* __restrict__ blocksum) {
  if (blockIdx.x < GEMM_BLOCKS) {
    mfma_gemm_body<9, false>(blockIdx.x, x, Wpk1, h1b, as1, ad1);
  } else {
    int b = blockIdx.x - GEMM_BLOCKS;
    int g = b * 256 + threadIdx.x;
    int v = bh[g];
    int total;
    int ex = block_excl_scan(v, &total);
    bhP[g] = ex;
    if (threadIdx.x == 0) blocksum[b] = total;
  }
}

__global__ __launch_bounds__(256) void gemm64_kernel(const uint4* __restrict__ h1eb,
                                                     const uint4* __restrict__ Wpk2,
                                                     unsigned* __restrict__ h2b,
                                                     float* __restrict__ as2, float* __restrict__ ad2) {
  mfma_gemm_body<5, true>(blockIdx.x, h1eb, Wpk2, h2b, as2, ad2);
}

// ---------------- scatter (top-scan recomputed locally in LDS) ----------------
__global__ __launch_bounds__(256) void scatter1_kernel(const int* __restrict__ ei, const int* __restrict__ bhP,
                                                       const int* __restrict__ blocksum, int2* __restrict__ eb) {
  __shared__ int cur[NB];
  __shared__ int boff[NB];
  int t = threadIdx.x;
  for (int i = t; i < NB; i += 256) cur[i] = 0;
  {
    int v = (t < NB) ? blocksum[t] : 0;
    int ex = block_excl_scan(v, nullptr);
    if (t < NB) boff[t] = ex;
  }
  __syncthreads();
  int start = blockIdx.x * EPB;
  for (int i = start + t; i < start + EPB; i += 256) {
    int dst = ei[N_EDGES + i];
    int src = ei[i];
    int bin = dst >> 8;
    int r = atomicAdd(&cur[bin], 1);
    int idx = bin * P1_BLOCKS + blockIdx.x;
    int pos = bhP[idx] + boff[bin] + r;
    eb[pos] = make_int2(src, dst);
  }
}

// ---------------- per-bucket fine sort -> rowptrF + col (top-scan recomputed locally) -------
__global__ __launch_bounds__(256) void bucket_csr_kernel(const int2* __restrict__ eb,
                                                         const int* __restrict__ blocksum,
                                                         int* __restrict__ rowptrF, int* __restrict__ col) {
  __shared__ int cnt[256];
  __shared__ int basel[256];
  __shared__ int cur[256];
  __shared__ int sse[2];
  int b = blockIdx.x;
  int t = threadIdx.x;
  {
    int v = (t < NB) ? blocksum[t] : 0;
    int ex0 = block_excl_scan(v, nullptr);
    if (t == b) sse[0] = ex0;
    if (t == b + 1) sse[1] = ex0;
  }
  cnt[t] = 0;
  cur[t] = 0;
  __syncthreads();
  int start = sse[0];
  int end = (b == NB - 1) ? N_EDGES : sse[1];
  for (int i = start + t; i < end; i += 256)
    atomicAdd(&cnt[eb[i].y & 255], 1);
  __syncthreads();
  int ex = block_excl_scan(cnt[t], nullptr);
  basel[t] = start + ex;
  int g = b * 256 + t;
  if (g < N_NODES) rowptrF[g] = start + ex;
  if (g == N_NODES) rowptrF[N_NODES] = N_EDGES;
  __syncthreads();
  for (int i = start + t; i < end; i += 256) {
    int2 e = eb[i];
    int d8 = e.y & 255;
    int r = atomicAdd(&cur[d8], 1);
    col[basel[d8] + r] = e.x;
  }
}

// ---------------- layer-1 gather, fused e-compute + denom; fp8 rows ----------------
__global__ __launch_bounds__(256) void agg1_kernel(const uint2* __restrict__ h1f8, const int* __restrict__ rowptr,
                                                   const int* __restrict__ col, const float* __restrict__ as1,
                                                   const float* __restrict__ ad1, const float4* __restrict__ b1v,
                                                   uint4* __restrict__ h1eb4) {
  int n = (blockIdx.x * 256 + threadIdx.x) >> 6;
  int lane = threadIdx.x & 63;
  int slot = lane >> 4;  // 0..3
  int fo = lane & 15;    // feats fo*8 .. fo*8+7
  int h = fo >> 2;       // head for these 8 feats
  int beg = rowptr[n], end = rowptr[n + 1];
  float adh = ad1[n * 4 + h];

  f32x2 acc2[4];
#pragma unroll
  for (int j = 0; j < 4; ++j) acc2[j] = (f32x2){0.f, 0.f};
  float esum = 0.f;

#define ACC_EDGE1(E)                                               \
  {                                                                \
    int src = col[E];                                              \
    float a = __expf(lrelu(as1[src * 4 + h] + adh));               \
    esum += a;                                                     \
    f32x2 av = {a, a};                                             \
    uint2 uu = h1f8[src * 16 + fo];                                \
    f32x2 p0 = __builtin_amdgcn_cvt_pk_f32_fp8(uu.x, false);       \
    f32x2 p1 = __builtin_amdgcn_cvt_pk_f32_fp8(uu.x, true);        \
    f32x2 p2 = __builtin_amdgcn_cvt_pk_f32_fp8(uu.y, false);       \
    f32x2 p3 = __builtin_amdgcn_cvt_pk_f32_fp8(uu.y, true);        \
    acc2[0] += av * p0; acc2[1] += av * p1;                        \
    acc2[2] += av * p2; acc2[3] += av * p3;                        \
  }

  int i = beg;
  for (; i + 16 <= end; i += 16) {
#pragma unroll
    for (int u = 0; u < 4; ++u) ACC_EDGE1(i + u * 4 + slot);
  }
  for (; i + 4 <= end; i += 4) ACC_EDGE1(i + slot);
  int rem = end - i;
  if (slot < rem) ACC_EDGE1(i + slot);
#undef ACC_EDGE1
  // self loop (slot 0 only)
  if (slot == 0) {
    float a = __expf(lrelu(as1[n * 4 + h] + adh));
    esum += a;
    f32x2 av = {a, a};
    uint2 uu = h1f8[n * 16 + fo];
    f32x2 p0 = __builtin_amdgcn_cvt_pk_f32_fp8(uu.x, false);
    f32x2 p1 = __builtin_amdgcn_cvt_pk_f32_fp8(uu.x, true);
    f32x2 p2 = __builtin_amdgcn_cvt_pk_f32_fp8(uu.y, false);
    f32x2 p3 = __builtin_amdgcn_cvt_pk_f32_fp8(uu.y, true);
    acc2[0] += av * p0; acc2[1] += av * p1;
    acc2[2] += av * p2; acc2[3] += av * p3;
  }
#pragma unroll
  for (int j = 0; j < 4; ++j) {
    acc2[j].x += __shfl_xor(acc2[j].x, 16);
    acc2[j].y += __shfl_xor(acc2[j].y, 16);
    acc2[j].x += __shfl_xor(acc2[j].x, 32);
    acc2[j].y += __shfl_xor(acc2[j].y, 32);
  }
  esum += __shfl_xor(esum, 16);
  esum += __shfl_xor(esum, 32);
  if (slot == 0) {
    float dsc = 1.f / esum;
    float4 b0 = b1v[fo * 2], b1 = b1v[fo * 2 + 1];
    float f0 = elu(acc2[0].x * dsc + b0.x), f1 = elu(acc2[0].y * dsc + b0.y);
    float f2 = elu(acc2[1].x * dsc + b0.z), f3 = elu(acc2[1].y * dsc + b0.w);
    float f4 = elu(acc2[2].x * dsc + b1.x), f5 = elu(acc2[2].y * dsc + b1.y);
    float f6 = elu(acc2[3].x * dsc + b1.z), f7 = elu(acc2[3].y * dsc + b1.w);
    uint4 o;
    o.x = pack2bf(f0, f1); o.y = pack2bf(f2, f3);
    o.z = pack2bf(f4, f5); o.w = pack2bf(f6, f7);
    h1eb4[n * 16 + fo] = o;  // h1e stays bf16 (feeds gemm64 MFMA A directly)
  }
}

// ---------------- layer-2 gather + pool; final linear folded in via last-block pattern -----
__global__ __launch_bounds__(256) void agg2_kernel(const uint2* __restrict__ h2f8, const int* __restrict__ rowptr,
                                                   const int* __restrict__ col, const float* __restrict__ as2,
                                                   const float* __restrict__ ad2, const float4* __restrict__ b2v,
                                                   float* __restrict__ pooled, const float* __restrict__ Wl,
                                                   const float* __restrict__ bl, float* __restrict__ out,
                                                   int* __restrict__ done) {
  __shared__ float red[4][64];
  __shared__ float pfin[64];
  __shared__ int lastf;
  int n = (blockIdx.x * 256 + threadIdx.x) >> 6;
  int lane = threadIdx.x & 63;
  int wid = threadIdx.x >> 6;
  int slot = lane >> 3;  // 0..7
  int fo = lane & 7;     // feats fo*8 .. fo*8+7
  int beg = rowptr[n], end = rowptr[n + 1];
  float ad = ad2[n];

  f32x2 acc2[4];
#pragma unroll
  for (int j = 0; j < 4; ++j) acc2[j] = (f32x2){0.f, 0.f};
  float esum = 0.f;

#define ACC_EDGE2(E)                                               \
  {                                                                \
    int src = col[E];                                              \
    float a = __expf(lrelu(as2[src] + ad));                        \
    esum += a;                                                     \
    f32x2 av = {a, a};                                             \
    uint2 uu = h2f8[src * 8 + fo];                                 \
    f32x2 p0 = __builtin_amdgcn_cvt_pk_f32_fp8(uu.x, false);       \
    f32x2 p1 = __builtin_amdgcn_cvt_pk_f32_fp8(uu.x, true);        \
    f32x2 p2 = __builtin_amdgcn_cvt_pk_f32_fp8(uu.y, false);       \
    f32x2 p3 = __builtin_amdgcn_cvt_pk_f32_fp8(uu.y, true);        \
    acc2[0] += av * p0; acc2[1] += av * p1;                        \
    acc2[2] += av * p2; acc2[3] += av * p3;                        \
  }

  int i = beg;
  for (; i + 32 <= end; i += 32) {
#pragma unroll
    for (int u = 0; u < 4; ++u) ACC_EDGE2(i + u * 8 + slot);
  }
  for (; i + 8 <= end; i += 8) ACC_EDGE2(i + slot);
  int rem = end - i;
  if (slot < rem) ACC_EDGE2(i + slot);
#undef ACC_EDGE2
  // self loop
  if (slot == 0) {
    float a = __expf(lrelu(as2[n] + ad));
    esum += a;
    f32x2 av = {a, a};
    uint2 uu = h2f8[n * 8 + fo];
    f32x2 p0 = __builtin_amdgcn_cvt_pk_f32_fp8(uu.x, false);
    f32x2 p1 = __builtin_amdgcn_cvt_pk_f32_fp8(uu.x, true);
    f32x2 p2 = __builtin_amdgcn_cvt_pk_f32_fp8(uu.y, false);
    f32x2 p3 = __builtin_amdgcn_cvt_pk_f32_fp8(uu.y, true);
    acc2[0] += av * p0; acc2[1] += av * p1;
    acc2[2] += av * p2; acc2[3] += av * p3;
  }
#pragma unroll
  for (int j = 0; j < 4; ++j) {
#pragma unroll
    for (int off = 8; off <= 32; off <<= 1) {
      acc2[j].x += __shfl_xor(acc2[j].x, off);
      acc2[j].y += __shfl_xor(acc2[j].y, off);
    }
  }
  esum += __shfl_xor(esum, 8);
  esum += __shfl_xor(esum, 16);
  esum += __shfl_xor(esum, 32);
  if (slot == 0) {
    float dsc = 1.f / esum;
    float4 b0 = b2v[fo * 2], b1 = b2v[fo * 2 + 1];
    red[wid][fo * 8 + 0] = elu(acc2[0].x * dsc + b0.x);
    red[wid][fo * 8 + 1] = elu(acc2[0].y * dsc + b0.y);
    red[wid][fo * 8 + 2] = elu(acc2[1].x * dsc + b0.z);
    red[wid][fo * 8 + 3] = elu(acc2[1].y * dsc + b0.w);
    red[wid][fo * 8 + 4] = elu(acc2[2].x * dsc + b1.x);
    red[wid][fo * 8 + 5] = elu(acc2[2].y * dsc + b1.y);
    red[wid][fo * 8 + 6] = elu(acc2[3].x * dsc + b1.z);
    red[wid][fo * 8 + 7] = elu(acc2[3].y * dsc + b1.w);
  }
  __syncthreads();
  if (threadIdx.x < 64) {
    float sum = red[0][threadIdx.x] + red[1][threadIdx.x] + red[2][threadIdx.x] + red[3][threadIdx.x];
    atomicAdd(&pooled[(blockIdx.x & 63) * 64 + threadIdx.x], sum);
  }
  // last block performs the final stripe-reduce + pooled@Wl+bl
  __syncthreads();
  if (threadIdx.x == 0) {
    __threadfence();
    lastf = (atomicAdd(done, 1) == AGG_BLOCKS - 1);
  }
  __syncthreads();
  if (lastf) {
    int t = threadIdx.x;
    if (t < 64) {
      float v = 0.f;
      for (int k = 0; k < 64; ++k)
        v += __hip_atomic_load(&pooled[k * 64 + t], __ATOMIC_RELAXED, __HIP_MEMORY_SCOPE_AGENT);
      pfin[t] = v;
      out[t] = v;
    }
    __syncthreads();
    if (t < 2) {
      float s = bl[t];
      for (int k = 0; k < 64; ++k) s += pfin[k] * Wl[k * 2 + t];
      out[64 + t] = s;
    }
  }
}

extern "C" void kernel_launch(void* const* d_in, const int* in_sizes, int n_in,
                              void* d_out, int out_size, void* d_ws, size_t ws_size,
                              hipStream_t stream) {
  (void)in_sizes; (void)n_in; (void)out_size; (void)ws_size;
  const float* x     = (const float*)d_in[0];
  const int*   ei    = (const int*)d_in[1];
  const float* W1    = (const float*)d_in[2];
  const float* atts1 = (const float*)d_in[3];
  const float* attd1 = (const float*)d_in[4];
  const float* b1    = (const float*)d_in[5];
  const float* W2    = (const float*)d_in[6];
  const float* atts2 = (const float*)d_in[7];
  const float* attd2 = (const float*)d_in[8];
  const float* b2    = (const float*)d_in[9];
  const float* Wl    = (const float*)d_in[10];
  const float* bl    = (const float*)d_in[11];
  float* out = (float*)d_out;

  char* w = (char*)d_ws;
  unsigned* h1b  = (unsigned*)w; w += (size_t)N_NODES * 128;      // 6.4 MB fp8
  unsigned* h1eb = (unsigned*)w; w += (size_t)N_NODES * 128 * 2;  // 12.8 MB bf16
  unsigned* h2b  = (unsigned*)w; w += (size_t)N_NODES * 64;       // 3.2 MB fp8
  float* as1  = (float*)w; w += (size_t)N_NODES * 16;
  float* ad1  = (float*)w; w += (size_t)N_NODES * 16;
  float* as2  = (float*)w; w += (size_t)N_NODES * 4;
  float* ad2  = (float*)w; w += (size_t)N_NODES * 4;
  float* pooled = (float*)w; w += 64 * 64 * 4;                    // 64 stripes x 64
  int* done   = (int*)w; w += 16;                                 // last-block counter
  uint4* Wpk1 = (uint4*)w; w += 4 * 9 * 64 * 16;                  // 36.9 KB packed bf16
  uint4* Wpk2 = (uint4*)w; w += 4 * 5 * 64 * 16;                  // 20.5 KB packed bf16
  int* rowptrF = (int*)w; w += (size_t)(N_NODES + 1) * 4 + 12;
  int* col    = (int*)w; w += (size_t)N_EDGES * 4;
  int2* eb    = (int2*)w; w += (size_t)N_EDGES * 8;               // bucket-ordered (src,dst)
  int* bh     = (int*)w; w += (size_t)BH_SIZE * 4;
  int* bhP    = (int*)w; w += (size_t)BH_SIZE * 4;
  int* blocksum = (int*)w; w += 256 * 4;

  // zero pooled stripes + done counter (contiguous)
  (void)hipMemsetAsync(pooled, 0, 64 * 64 * 4 + 16, stream);

  // D1: weight pack (2 blocks) || coarse histogram (256 blocks)
  setup_hist_kernel<<<258, 256, 0, stream>>>(ei, bh, W1, atts1, attd1, W2, atts2, attd2, Wpk1, Wpk2);
  // D2: MFMA gemm128+att (782 blocks) || bh partial scan (196 blocks)
  gemm128_scan_kernel<<<GEMM_BLOCKS + NB, 256, 0, stream>>>(x, Wpk1, h1b, as1, ad1, bh, bhP, blocksum);
  // D3: scatter into bucket order (top-scan recomputed in LDS)
  scatter1_kernel<<<P1_BLOCKS, 256, 0, stream>>>(ei, bhP, blocksum, eb);
  // D4: per-bucket fine sort -> CSR
  bucket_csr_kernel<<<NB, 256, 0, stream>>>(eb, blocksum, rowptrF, col);
  // D5: layer-1 softmax-aggregate
  agg1_kernel<<<AGG_BLOCKS, 256, 0, stream>>>((const uint2*)h1b, rowptrF, col, as1, ad1,
                                              (const float4*)b1, (uint4*)h1eb);
  // D6: MFMA gemm64+att (bf16 A direct)
  gemm64_kernel<<<GEMM_BLOCKS, 256, 0, stream>>>((const uint4*)h1eb, Wpk2, h2b, as2, ad2);
  // D7: layer-2 softmax-aggregate + pool + fused final linear
  agg2_kernel<<<AGG_BLOCKS, 256, 0, stream>>>((const uint2*)h2b, rowptrF, col, as2, ad2,
                                              (const float4*)b2, pooled, Wl, bl, out, done);
}

// Round 2
// 206.130 us; speedup vs baseline: 2.0972x; 2.0972x over previous
//
#include <hip/hip_runtime.h>

#define N_NODES 50000
#define N_EDGES 800000
#define NB 196                        // buckets = ceil(50000/256)
#define P1_BLOCKS 256                 // hist/scatter blocks
#define EPB 3125                      // edges per block (256*3125 = 800000)
#define BH_SIZE (NB * P1_BLOCKS)      // 50176
#define GEMM_BLOCKS ((N_NODES + 63) / 64)     // 782
#define AGG_BLOCKS (N_NODES / 4)              // 12500

__device__ __forceinline__ float lrelu(float x) { return fmaxf(x, 0.2f * x); }
__device__ __forceinline__ float elu(float x) { return x > 0.f ? x : __expf(x) - 1.f; }

typedef float f32x2 __attribute__((ext_vector_type(2)));
typedef float f32x4v __attribute__((ext_vector_type(4)));
typedef short bf16x8 __attribute__((ext_vector_type(8)));

__device__ __forceinline__ unsigned f2bf_rn(float x) {
  unsigned u = __float_as_uint(x);
  return (u + 0x7fffu + ((u >> 16) & 1u)) >> 16;
}
__device__ __forceinline__ unsigned pack2bf(float a, float b) {
  return f2bf_rn(a) | (f2bf_rn(b) << 16);
}
__device__ __forceinline__ uint4 pack8bf(const float* v) {
  uint4 o;
  o.x = pack2bf(v[0], v[1]); o.y = pack2bf(v[2], v[3]);
  o.z = pack2bf(v[4], v[5]); o.w = pack2bf(v[6], v[7]);
  return o;
}

__device__ __forceinline__ int block_excl_scan(int v, int* total_out) {
  int lane = threadIdx.x & 63;
  int wid = threadIdx.x >> 6;
  int x = v;
#pragma unroll
  for (int off = 1; off < 64; off <<= 1) {
    int u = __shfl_up(x, off);
    if (lane >= off) x += u;
  }
  __shared__ int wsum[4];
  if (lane == 63) wsum[wid] = x;
  __syncthreads();
  int add = 0;
#pragma unroll
  for (int k = 0; k < 4; ++k)
    if (k < wid) add += wsum[k];
  if (total_out) *total_out = wsum[0] + wsum[1] + wsum[2] + wsum[3];
  return x + add - v;
}

// ---------------- dispatch 1: weight pack (blocks 0,1) || edge histogram (blocks 2..257) ----
// Packed layout for MFMA B-frags: Wpk[(ks*NF + f)*64 + lane] = 8 bf16 with
//   col = f*16 + (lane&15), k = ks*32 + (lane>>4)*8 + j   (j = 0..7)
// Layer1 cols: 0..127 = W1; 128+h = W1·atts1 (head h); 132+h = W1·attd1; 136..143 = 0.
// Layer2 cols: 0..63 = W2; 64 = W2·atts2; 65 = W2·attd2; 66..79 = 0.
__global__ __launch_bounds__(256) void setup_hist_kernel(
    const int* __restrict__ ei, int* __restrict__ bh,
    const float* __restrict__ W1, const float* __restrict__ atts1, const float* __restrict__ attd1,
    const float* __restrict__ W2, const float* __restrict__ atts2, const float* __restrict__ attd2,
    uint4* __restrict__ Wpk1, uint4* __restrict__ Wpk2) {
  __shared__ int cnt[NB];
  int bid = blockIdx.x;
  if (bid >= 2) {
    for (int t = threadIdx.x; t < NB; t += 256) cnt[t] = 0;
    __syncthreads();
    int start = (bid - 2) * EPB;
    for (int i = start + threadIdx.x; i < start + EPB; i += 256)
      atomicAdd(&cnt[ei[N_EDGES + i] >> 8], 1);
    __syncthreads();
    for (int t = threadIdx.x; t < NB; t += 256)
      bh[t * P1_BLOCKS + (bid - 2)] = cnt[t];
    return;
  }
  if (bid == 0) {
    for (int s = threadIdx.x; s < 4 * 9 * 64; s += 256) {
      int l = s & 63, sf = s >> 6;
      int f = sf % 9, ks = sf / 9;
      int colb = f * 16 + (l & 15);
      int kb = ks * 32 + ((l >> 4) << 3);
      float v[8];
      if (colb < 128) {
#pragma unroll
        for (int j = 0; j < 8; ++j) v[j] = W1[(kb + j) * 128 + colb];
      } else if (colb < 136) {
        int cc = colb - 128;
        const float* at = (cc < 4) ? atts1 : attd1;
        int h = cc & 3;
#pragma unroll
        for (int j = 0; j < 8; ++j) {
          float s2 = 0.f;
          for (int q = 0; q < 32; ++q) s2 += W1[(kb + j) * 128 + h * 32 + q] * at[h * 32 + q];
          v[j] = s2;
        }
      } else {
#pragma unroll
        for (int j = 0; j < 8; ++j) v[j] = 0.f;
      }
      Wpk1[s] = pack8bf(v);
    }
  } else {
    for (int s = threadIdx.x; s < 4 * 5 * 64; s += 256) {
      int l = s & 63, sf = s >> 6;
      int f = sf % 5, ks = sf / 5;
      int colb = f * 16 + (l & 15);
      int kb = ks * 32 + ((l >> 4) << 3);
      float v[8];
      if (colb < 64) {
#pragma unroll
        for (int j = 0; j < 8; ++j) v[j] = W2[(kb + j) * 64 + colb];
      } else if (colb < 66) {
        const float* at = (colb == 64) ? atts2 : attd2;
#pragma unroll
        for (int j = 0; j < 8; ++j) {
          float s2 = 0.f;
          for (int q = 0; q < 64; ++q) s2 += W2[(kb + j) * 64 + q] * at[q];
          v[j] = s2;
        }
      } else {
#pragma unroll
        for (int j = 0; j < 8; ++j) v[j] = 0.f;
      }
      Wpk2[s] = pack8bf(v);
    }
  }
}

// ---------------- MFMA GEMM body: 64 rows x (NF*16) cols, K=128, 4 waves ----------------
// A staged as bf16 in LDS, stride 136 (granule-bank-rotating: conflict-free b128 frag reads).
// B = packed Wpk staged linearly (lane-consecutive 16B reads, conflict-free).
// Last col-frag = attention dots (as | ad). Other frags packed to fp8 e4m3 via lane shuffles.
template <int NF, bool ABF16>
__device__ __forceinline__ void mfma_gemm_body(int bx, const void* __restrict__ Ap,
                                               const uint4* __restrict__ Wpk,
                                               unsigned* __restrict__ Yb,
                                               float* __restrict__ as_out, float* __restrict__ ad_out) {
  __shared__ unsigned short Xs[64 * 136];
  __shared__ uint4 Ws[NF * 256];
  int t = threadIdx.x;
  int rbase = bx * 64;
#pragma unroll
  for (int p = 0; p < NF; ++p) Ws[p * 256 + t] = Wpk[p * 256 + t];
  if constexpr (ABF16) {
    const uint4* A4 = (const uint4*)Ap;   // row = 128 bf16 = 16 uint4
#pragma unroll
    for (int p = 0; p < 4; ++p) {
      int i = p * 256 + t;
      int row = i >> 4, q = i & 15;
      int gr = rbase + row; if (gr > N_NODES - 1) gr = N_NODES - 1;
      *(uint4*)&Xs[row * 136 + q * 8] = A4[gr * 16 + q];
    }
  } else {
    const float4* A4 = (const float4*)Ap; // row = 32 float4
#pragma unroll
    for (int p = 0; p < 8; ++p) {
      int i = p * 256 + t;
      int row = i >> 5, q = i & 31;
      int gr = rbase + row; if (gr > N_NODES - 1) gr = N_NODES - 1;
      float4 v = A4[gr * 32 + q];
      *(uint2*)&Xs[row * 136 + q * 4] = make_uint2(pack2bf(v.x, v.y), pack2bf(v.z, v.w));
    }
  }
  __syncthreads();

  int l = t & 63, wv = t >> 6;
  int lc = l & 15, lk = l >> 4;
  f32x4v acc[NF];
#pragma unroll
  for (int f = 0; f < NF; ++f) acc[f] = (f32x4v){0.f, 0.f, 0.f, 0.f};
  const unsigned short* ap = &Xs[(wv * 16 + lc) * 136 + lk * 8];
#pragma unroll
  for (int ks = 0; ks < 4; ++ks) {
    bf16x8 a = *(const bf16x8*)(ap + ks * 32);
#pragma unroll
    for (int f = 0; f < NF; ++f) {
      bf16x8 b = *(const bf16x8*)&Ws[(ks * NF + f) * 64 + l];
      acc[f] = __builtin_amdgcn_mfma_f32_16x16x32_bf16(a, b, acc[f], 0, 0, 0);
    }
  }

  // C/D layout: col = f*16 + (lane&15), row = (lane>>4)*4 + reg
  constexpr int NCF = NF - 1;
#pragma unroll
  for (int reg = 0; reg < 4; ++reg) {
    int row = rbase + wv * 16 + lk * 4 + reg;
    bool rok = row < N_NODES;
    float av = acc[NCF][reg];
    if (rok) {
      if constexpr (NF == 9) {
        if (lc < 4) as_out[row * 4 + lc] = av;
        else if (lc < 8) ad_out[row * 4 + lc - 4] = av;
      } else {
        if (lc == 0) as_out[row] = av;
        else if (lc == 1) ad_out[row] = av;
      }
    }
    unsigned words[NCF];
#pragma unroll
    for (int f = 0; f < NCF; ++f) {
      float v = acc[f][reg];
      float n1 = __shfl_xor(v, 1);
      unsigned pk = (unsigned)__builtin_amdgcn_cvt_pk_fp8_f32(v, n1, 0, false);  // valid on even lanes
      unsigned pk2 = (unsigned)__shfl_xor((int)pk, 2);
      words[f] = (pk & 0xffffu) | (pk2 << 16);
    }
    if (rok && (lc & 3) == 0) {
#pragma unroll
      for (int f = 0; f < NCF; ++f)
        Yb[row * (NCF * 4) + f * 4 + (lc >> 2)] = words[f];
    }
  }
}

// ---------------- dispatch 2: gemm128 (blocks 0..781) || bh partial scan (782..977) --------
__global__ __launch_bounds__(256) void gemm128_scan_kernel(
    const float* __restrict__ x, const uint4* __restrict__ Wpk1,
    unsigned* __restrict__ h1b, float* __restrict__ as1, float* __restrict__ ad1,
    const int* __restrict__ bh, int* __restrict__ bhP, int* __restrict__ blocksum) {
  if (blockIdx.x < GEMM_BLOCKS) {
    mfma_gemm_body<9, false>(blockIdx.x, x, Wpk1, h1b, as1, ad1);
  } else {
    int b = blockIdx.x - GEMM_BLOCKS;
    int g = b * 256 + threadIdx.x;
    int v = bh[g];
    int total;
    int ex = block_excl_scan(v, &total);
    bhP[g] = ex;
    if (threadIdx.x == 0) blocksum[b] = total;
  }
}

__global__ __launch_bounds__(256) void gemm64_kernel(const uint4* __restrict__ h1eb,
                                                     const uint4* __restrict__ Wpk2,
                                                     unsigned* __restrict__ h2b,
                                                     float* __restrict__ as2, float* __restrict__ ad2) {
  mfma_gemm_body<5, true>(blockIdx.x, h1eb, Wpk2, h2b, as2, ad2);
}

// ---------------- scatter (top-scan recomputed locally in LDS) ----------------
__global__ __launch_bounds__(256) void scatter1_kernel(const int* __restrict__ ei, const int* __restrict__ bhP,
                                                       const int* __restrict__ blocksum, int2* __restrict__ eb) {
  __shared__ int cur[NB];
  __shared__ int boff[NB];
  int t = threadIdx.x;
  for (int i = t; i < NB; i += 256) cur[i] = 0;
  {
    int v = (t < NB) ? blocksum[t] : 0;
    int ex = block_excl_scan(v, nullptr);
    if (t < NB) boff[t] = ex;
  }
  __syncthreads();
  int start = blockIdx.x * EPB;
  for (int i = start + t; i < start + EPB; i += 256) {
    int dst = ei[N_EDGES + i];
    int src = ei[i];
    int bin = dst >> 8;
    int r = atomicAdd(&cur[bin], 1);
    int idx = bin * P1_BLOCKS + blockIdx.x;
    int pos = bhP[idx] + boff[bin] + r;
    eb[pos] = make_int2(src, dst);
  }
}

// ---------------- per-bucket fine sort -> rowptrF + col (top-scan recomputed locally) -------
__global__ __launch_bounds__(256) void bucket_csr_kernel(const int2* __restrict__ eb,
                                                         const int* __restrict__ blocksum,
                                                         int* __restrict__ rowptrF, int* __restrict__ col) {
  __shared__ int cnt[256];
  __shared__ int basel[256];
  __shared__ int cur[256];
  __shared__ int sse[2];
  int b = blockIdx.x;
  int t = threadIdx.x;
  {
    int v = (t < NB) ? blocksum[t] : 0;
    int ex0 = block_excl_scan(v, nullptr);
    if (t == b) sse[0] = ex0;
    if (t == b + 1) sse[1] = ex0;
  }
  cnt[t] = 0;
  cur[t] = 0;
  __syncthreads();
  int start = sse[0];
  int end = (b == NB - 1) ? N_EDGES : sse[1];
  for (int i = start + t; i < end; i += 256)
    atomicAdd(&cnt[eb[i].y & 255], 1);
  __syncthreads();
  int ex = block_excl_scan(cnt[t], nullptr);
  basel[t] = start + ex;
  int g = b * 256 + t;
  if (g < N_NODES) rowptrF[g] = start + ex;
  if (g == N_NODES) rowptrF[N_NODES] = N_EDGES;
  __syncthreads();
  for (int i = start + t; i < end; i += 256) {
    int2 e = eb[i];
    int d8 = e.y & 255;
    int r = atomicAdd(&cur[d8], 1);
    col[basel[d8] + r] = e.x;
  }
}

// ---------------- layer-1 gather, fused e-compute + denom; fp8 rows ----------------
__global__ __launch_bounds__(256) void agg1_kernel(const uint2* __restrict__ h1f8, const int* __restrict__ rowptr,
                                                   const int* __restrict__ col, const float* __restrict__ as1,
                                                   const float* __restrict__ ad1, const float4* __restrict__ b1v,
                                                   uint4* __restrict__ h1eb4) {
  int n = (blockIdx.x * 256 + threadIdx.x) >> 6;
  int lane = threadIdx.x & 63;
  int slot = lane >> 4;  // 0..3
  int fo = lane & 15;    // feats fo*8 .. fo*8+7
  int h = fo >> 2;       // head for these 8 feats
  int beg = rowptr[n], end = rowptr[n + 1];
  float adh = ad1[n * 4 + h];

  f32x2 acc2[4];
#pragma unroll
  for (int j = 0; j < 4; ++j) acc2[j] = (f32x2){0.f, 0.f};
  float esum = 0.f;

#define ACC_EDGE1(E)                                               \
  {                                                                \
    int src = col[E];                                              \
    float a = __expf(lrelu(as1[src * 4 + h] + adh));               \
    esum += a;                                                     \
    f32x2 av = {a, a};                                             \
    uint2 uu = h1f8[src * 16 + fo];                                \
    f32x2 p0 = __builtin_amdgcn_cvt_pk_f32_fp8(uu.x, false);       \
    f32x2 p1 = __builtin_amdgcn_cvt_pk_f32_fp8(uu.x, true);        \
    f32x2 p2 = __builtin_amdgcn_cvt_pk_f32_fp8(uu.y, false);       \
    f32x2 p3 = __builtin_amdgcn_cvt_pk_f32_fp8(uu.y, true);        \
    acc2[0] += av * p0; acc2[1] += av * p1;                        \
    acc2[2] += av * p2; acc2[3] += av * p3;                        \
  }

  int i = beg;
  for (; i + 16 <= end; i += 16) {
#pragma unroll
    for (int u = 0; u < 4; ++u) ACC_EDGE1(i + u * 4 + slot);
  }
  for (; i + 4 <= end; i += 4) ACC_EDGE1(i + slot);
  int rem = end - i;
  if (slot < rem) ACC_EDGE1(i + slot);
#undef ACC_EDGE1
  // self loop (slot 0 only)
  if (slot == 0) {
    float a = __expf(lrelu(as1[n * 4 + h] + adh));
    esum += a;
    f32x2 av = {a, a};
    uint2 uu = h1f8[n * 16 + fo];
    f32x2 p0 = __builtin_amdgcn_cvt_pk_f32_fp8(uu.x, false);
    f32x2 p1 = __builtin_amdgcn_cvt_pk_f32_fp8(uu.x, true);
    f32x2 p2 = __builtin_amdgcn_cvt_pk_f32_fp8(uu.y, false);
    f32x2 p3 = __builtin_amdgcn_cvt_pk_f32_fp8(uu.y, true);
    acc2[0] += av * p0; acc2[1] += av * p1;
    acc2[2] += av * p2; acc2[3] += av * p3;
  }
#pragma unroll
  for (int j = 0; j < 4; ++j) {
    acc2[j].x += __shfl_xor(acc2[j].x, 16);
    acc2[j].y += __shfl_xor(acc2[j].y, 16);
    acc2[j].x += __shfl_xor(acc2[j].x, 32);
    acc2[j].y += __shfl_xor(acc2[j].y, 32);
  }
  esum += __shfl_xor(esum, 16);
  esum += __shfl_xor(esum, 32);
  if (slot == 0) {
    float dsc = 1.f / esum;
    float4 b0 = b1v[fo * 2], b1 = b1v[fo * 2 + 1];
    float f0 = elu(acc2[0].x * dsc + b0.x), f1 = elu(acc2[0].y * dsc + b0.y);
    float f2 = elu(acc2[1].x * dsc + b0.z), f3 = elu(acc2[1].y * dsc + b0.w);
    float f4 = elu(acc2[2].x * dsc + b1.x), f5 = elu(acc2[2].y * dsc + b1.y);
    float f6 = elu(acc2[3].x * dsc + b1.z), f7 = elu(acc2[3].y * dsc + b1.w);
    uint4 o;
    o.x = pack2bf(f0, f1); o.y = pack2bf(f2, f3);
    o.z = pack2bf(f4, f5); o.w = pack2bf(f6, f7);
    h1eb4[n * 16 + fo] = o;  // h1e stays bf16 (feeds gemm64 MFMA A directly)
  }
}

// ---------------- layer-2 gather, fused e + denom + global add pool; fp8 rows ----------------
// NOTE: no __threadfence / last-block fusion here — per-block device-scope fences on gfx950
// trigger per-XCD L2 writeback/invalidate maintenance and cost ~220 µs across 12500 blocks
// (measured round 1: agg2 263 µs @ 80 GB/s, 6% VALUBusy). Separate 1-block final_kernel is
// ~5 µs of launch overhead instead.
__global__ __launch_bounds__(256) void agg2_kernel(const uint2* __restrict__ h2f8, const int* __restrict__ rowptr,
                                                   const int* __restrict__ col, const float* __restrict__ as2,
                                                   const float* __restrict__ ad2, const float4* __restrict__ b2v,
                                                   float* __restrict__ pooled) {
  __shared__ float red[4][64];
  int n = (blockIdx.x * 256 + threadIdx.x) >> 6;
  int lane = threadIdx.x & 63;
  int wid = threadIdx.x >> 6;
  int slot = lane >> 3;  // 0..7
  int fo = lane & 7;     // feats fo*8 .. fo*8+7
  int beg = rowptr[n], end = rowptr[n + 1];
  float ad = ad2[n];

  f32x2 acc2[4];
#pragma unroll
  for (int j = 0; j < 4; ++j) acc2[j] = (f32x2){0.f, 0.f};
  float esum = 0.f;

#define ACC_EDGE2(E)                                               \
  {                                                                \
    int src = col[E];                                              \
    float a = __expf(lrelu(as2[src] + ad));                        \
    esum += a;                                                     \
    f32x2 av = {a, a};                                             \
    uint2 uu = h2f8[src * 8 + fo];                                 \
    f32x2 p0 = __builtin_amdgcn_cvt_pk_f32_fp8(uu.x, false);       \
    f32x2 p1 = __builtin_amdgcn_cvt_pk_f32_fp8(uu.x, true);        \
    f32x2 p2 = __builtin_amdgcn_cvt_pk_f32_fp8(uu.y, false);       \
    f32x2 p3 = __builtin_amdgcn_cvt_pk_f32_fp8(uu.y, true);        \
    acc2[0] += av * p0; acc2[1] += av * p1;                        \
    acc2[2] += av * p2; acc2[3] += av * p3;                        \
  }

  int i = beg;
  for (; i + 32 <= end; i += 32) {
#pragma unroll
    for (int u = 0; u < 4; ++u) ACC_EDGE2(i + u * 8 + slot);
  }
  for (; i + 8 <= end; i += 8) ACC_EDGE2(i + slot);
  int rem = end - i;
  if (slot < rem) ACC_EDGE2(i + slot);
#undef ACC_EDGE2
  // self loop
  if (slot == 0) {
    float a = __expf(lrelu(as2[n] + ad));
    esum += a;
    f32x2 av = {a, a};
    uint2 uu = h2f8[n * 8 + fo];
    f32x2 p0 = __builtin_amdgcn_cvt_pk_f32_fp8(uu.x, false);
    f32x2 p1 = __builtin_amdgcn_cvt_pk_f32_fp8(uu.x, true);
    f32x2 p2 = __builtin_amdgcn_cvt_pk_f32_fp8(uu.y, false);
    f32x2 p3 = __builtin_amdgcn_cvt_pk_f32_fp8(uu.y, true);
    acc2[0] += av * p0; acc2[1] += av * p1;
    acc2[2] += av * p2; acc2[3] += av * p3;
  }
#pragma unroll
  for (int j = 0; j < 4; ++j) {
#pragma unroll
    for (int off = 8; off <= 32; off <<= 1) {
      acc2[j].x += __shfl_xor(acc2[j].x, off);
      acc2[j].y += __shfl_xor(acc2[j].y, off);
    }
  }
  esum += __shfl_xor(esum, 8);
  esum += __shfl_xor(esum, 16);
  esum += __shfl_xor(esum, 32);
  if (slot == 0) {
    float dsc = 1.f / esum;
    float4 b0 = b2v[fo * 2], b1 = b2v[fo * 2 + 1];
    red[wid][fo * 8 + 0] = elu(acc2[0].x * dsc + b0.x);
    red[wid][fo * 8 + 1] = elu(acc2[0].y * dsc + b0.y);
    red[wid][fo * 8 + 2] = elu(acc2[1].x * dsc + b0.z);
    red[wid][fo * 8 + 3] = elu(acc2[1].y * dsc + b0.w);
    red[wid][fo * 8 + 4] = elu(acc2[2].x * dsc + b1.x);
    red[wid][fo * 8 + 5] = elu(acc2[2].y * dsc + b1.y);
    red[wid][fo * 8 + 6] = elu(acc2[3].x * dsc + b1.z);
    red[wid][fo * 8 + 7] = elu(acc2[3].y * dsc + b1.w);
  }
  __syncthreads();
  if (threadIdx.x < 64) {
    float sum = red[0][threadIdx.x] + red[1][threadIdx.x] + red[2][threadIdx.x] + red[3][threadIdx.x];
    atomicAdd(&pooled[(blockIdx.x & 63) * 64 + threadIdx.x], sum);
  }
}

// ---------------- final: reduce pooled stripes + pooled@Wl+bl ----------------
__global__ void final_kernel(const float* __restrict__ pooledS, const float* __restrict__ Wl,
                             const float* __restrict__ bl, float* __restrict__ out) {
  __shared__ float p[64];
  int t = threadIdx.x;
  float v = 0.f;
  for (int k = 0; k < 64; ++k) v += pooledS[k * 64 + t];
  p[t] = v;
  out[t] = v;
  __syncthreads();
  if (t < 2) {
    float s = bl[t];
    for (int k = 0; k < 64; ++k) s += p[k] * Wl[k * 2 + t];
    out[64 + t] = s;
  }
}

extern "C" void kernel_launch(void* const* d_in, const int* in_sizes, int n_in,
                              void* d_out, int out_size, void* d_ws, size_t ws_size,
                              hipStream_t stream) {
  (void)in_sizes; (void)n_in; (void)out_size; (void)ws_size;
  const float* x     = (const float*)d_in[0];
  const int*   ei    = (const int*)d_in[1];
  const float* W1    = (const float*)d_in[2];
  const float* atts1 = (const float*)d_in[3];
  const float* attd1 = (const float*)d_in[4];
  const float* b1    = (const float*)d_in[5];
  const float* W2    = (const float*)d_in[6];
  const float* atts2 = (const float*)d_in[7];
  const float* attd2 = (const float*)d_in[8];
  const float* b2    = (const float*)d_in[9];
  const float* Wl    = (const float*)d_in[10];
  const float* bl    = (const float*)d_in[11];
  float* out = (float*)d_out;

  char* w = (char*)d_ws;
  unsigned* h1b  = (unsigned*)w; w += (size_t)N_NODES * 128;      // 6.4 MB fp8
  unsigned* h1eb = (unsigned*)w; w += (size_t)N_NODES * 128 * 2;  // 12.8 MB bf16
  unsigned* h2b  = (unsigned*)w; w += (size_t)N_NODES * 64;       // 3.2 MB fp8
  float* as1  = (float*)w; w += (size_t)N_NODES * 16;
  float* ad1  = (float*)w; w += (size_t)N_NODES * 16;
  float* as2  = (float*)w; w += (size_t)N_NODES * 4;
  float* ad2  = (float*)w; w += (size_t)N_NODES * 4;
  float* pooled = (float*)w; w += 64 * 64 * 4;                    // 64 stripes x 64
  uint4* Wpk1 = (uint4*)w; w += 4 * 9 * 64 * 16;                  // 36.9 KB packed bf16
  uint4* Wpk2 = (uint4*)w; w += 4 * 5 * 64 * 16;                  // 20.5 KB packed bf16
  int* rowptrF = (int*)w; w += (size_t)(N_NODES + 1) * 4 + 12;
  int* col    = (int*)w; w += (size_t)N_EDGES * 4;
  int2* eb    = (int2*)w; w += (size_t)N_EDGES * 8;               // bucket-ordered (src,dst)
  int* bh     = (int*)w; w += (size_t)BH_SIZE * 4;
  int* bhP    = (int*)w; w += (size_t)BH_SIZE * 4;
  int* blocksum = (int*)w; w += 256 * 4;

  // zero pooled only
  (void)hipMemsetAsync(pooled, 0, 64 * 64 * 4, stream);

  // D1: weight pack (2 blocks) || coarse histogram (256 blocks)
  setup_hist_kernel<<<258, 256, 0, stream>>>(ei, bh, W1, atts1, attd1, W2, atts2, attd2, Wpk1, Wpk2);
  // D2: MFMA gemm128+att (782 blocks) || bh partial scan (196 blocks)
  gemm128_scan_kernel<<<GEMM_BLOCKS + NB, 256, 0, stream>>>(x, Wpk1, h1b, as1, ad1, bh, bhP, blocksum);
  // D3: scatter into bucket order (top-scan recomputed in LDS)
  scatter1_kernel<<<P1_BLOCKS, 256, 0, stream>>>(ei, bhP, blocksum, eb);
  // D4: per-bucket fine sort -> CSR
  bucket_csr_kernel<<<NB, 256, 0, stream>>>(eb, blocksum, rowptrF, col);
  // D5: layer-1 softmax-aggregate
  agg1_kernel<<<AGG_BLOCKS, 256, 0, stream>>>((const uint2*)h1b, rowptrF, col, as1, ad1,
                                              (const float4*)b1, (uint4*)h1eb);
  // D6: MFMA gemm64+att (bf16 A direct)
  gemm64_kernel<<<GEMM_BLOCKS, 256, 0, stream>>>((const uint4*)h1eb, Wpk2, h2b, as2, ad2);
  // D7: layer-2 softmax-aggregate + pool
  agg2_kernel<<<AGG_BLOCKS, 256, 0, stream>>>((const uint2*)h2b, rowptrF, col, as2, ad2,
                                              (const float4*)b2, pooled);
  // D8: reduce stripes + final linear
  final_kernel<<<1, 64, 0, stream>>>(pooled, Wl, bl, out);
}

// Round 3
// 204.881 us; speedup vs baseline: 2.1100x; 1.0061x over previous
//
#include <hip/hip_runtime.h>

#define N_NODES 50000
#define N_EDGES 800000
#define NB 196                        // buckets = ceil(50000/256)
#define P1_BLOCKS 256                 // hist/scatter blocks
#define EPB 3125                      // edges per block (256*3125 = 800000)
#define BH_SIZE (NB * P1_BLOCKS)      // 50176
#define GEMM_BLOCKS ((N_NODES + 63) / 64)     // 782
#define AGG_BLOCKS (N_NODES / 4)              // 12500
#define EBS_CAP 5120                  // bucket stage capacity (mean 4096, sigma ~64)

__device__ __forceinline__ float lrelu(float x) { return fmaxf(x, 0.2f * x); }
__device__ __forceinline__ float elu(float x) { return x > 0.f ? x : __expf(x) - 1.f; }

typedef float f32x2 __attribute__((ext_vector_type(2)));
typedef float f32x4v __attribute__((ext_vector_type(4)));
typedef short bf16x8 __attribute__((ext_vector_type(8)));

__device__ __forceinline__ unsigned f2bf_rn(float x) {
  unsigned u = __float_as_uint(x);
  return (u + 0x7fffu + ((u >> 16) & 1u)) >> 16;
}
__device__ __forceinline__ unsigned pack2bf(float a, float b) {
  return f2bf_rn(a) | (f2bf_rn(b) << 16);
}
__device__ __forceinline__ uint4 pack8bf(const float* v) {
  uint4 o;
  o.x = pack2bf(v[0], v[1]); o.y = pack2bf(v[2], v[3]);
  o.z = pack2bf(v[4], v[5]); o.w = pack2bf(v[6], v[7]);
  return o;
}

__device__ __forceinline__ int block_excl_scan(int v, int* total_out) {
  int lane = threadIdx.x & 63;
  int wid = threadIdx.x >> 6;
  int x = v;
#pragma unroll
  for (int off = 1; off < 64; off <<= 1) {
    int u = __shfl_up(x, off);
    if (lane >= off) x += u;
  }
  __shared__ int wsum[4];
  if (lane == 63) wsum[wid] = x;
  __syncthreads();
  int add = 0;
#pragma unroll
  for (int k = 0; k < 4; ++k)
    if (k < wid) add += wsum[k];
  if (total_out) *total_out = wsum[0] + wsum[1] + wsum[2] + wsum[3];
  return x + add - v;
}

// ---------------- dispatch 1: weight pack (blocks 0,1) || edge histogram (blocks 2..257) ----
// Packed layout for MFMA B-frags: Wpk[(ks*NF + f)*64 + lane] = 8 bf16 with
//   col = f*16 + (lane&15), k = ks*32 + (lane>>4)*8 + j   (j = 0..7)
// Layer1 cols: 0..127 = W1; 128+h = W1·atts1 (head h); 132+h = W1·attd1; 136..143 = 0.
// Layer2 cols: 0..63 = W2; 64 = W2·atts2; 65 = W2·attd2; 66..79 = 0.
// Block 1 also zeroes the pooled stripes (consumed first at D7) -> no memset dispatch.
__global__ __launch_bounds__(256) void setup_hist_kernel(
    const int* __restrict__ ei, int* __restrict__ bh,
    const float* __restrict__ W1, const float* __restrict__ atts1, const float* __restrict__ attd1,
    const float* __restrict__ W2, const float* __restrict__ atts2, const float* __restrict__ attd2,
    uint4* __restrict__ Wpk1, uint4* __restrict__ Wpk2, float* __restrict__ pooled) {
  __shared__ int cnt[NB];
  int bid = blockIdx.x;
  if (bid >= 2) {
    for (int t = threadIdx.x; t < NB; t += 256) cnt[t] = 0;
    __syncthreads();
    int start = (bid - 2) * EPB;
    for (int i = start + threadIdx.x; i < start + EPB; i += 256)
      atomicAdd(&cnt[ei[N_EDGES + i] >> 8], 1);
    __syncthreads();
    for (int t = threadIdx.x; t < NB; t += 256)
      bh[t * P1_BLOCKS + (bid - 2)] = cnt[t];
    return;
  }
  if (bid == 0) {
    for (int s = threadIdx.x; s < 4 * 9 * 64; s += 256) {
      int l = s & 63, sf = s >> 6;
      int f = sf % 9, ks = sf / 9;
      int colb = f * 16 + (l & 15);
      int kb = ks * 32 + ((l >> 4) << 3);
      float v[8];
      if (colb < 128) {
#pragma unroll
        for (int j = 0; j < 8; ++j) v[j] = W1[(kb + j) * 128 + colb];
      } else if (colb < 136) {
        int cc = colb - 128;
        const float* at = (cc < 4) ? atts1 : attd1;
        int h = cc & 3;
#pragma unroll
        for (int j = 0; j < 8; ++j) {
          float s2 = 0.f;
          for (int q = 0; q < 32; ++q) s2 += W1[(kb + j) * 128 + h * 32 + q] * at[h * 32 + q];
          v[j] = s2;
        }
      } else {
#pragma unroll
        for (int j = 0; j < 8; ++j) v[j] = 0.f;
      }
      Wpk1[s] = pack8bf(v);
    }
  } else {
    for (int s = threadIdx.x; s < 4 * 5 * 64; s += 256) {
      int l = s & 63, sf = s >> 6;
      int f = sf % 5, ks = sf / 5;
      int colb = f * 16 + (l & 15);
      int kb = ks * 32 + ((l >> 4) << 3);
      float v[8];
      if (colb < 64) {
#pragma unroll
        for (int j = 0; j < 8; ++j) v[j] = W2[(kb + j) * 64 + colb];
      } else if (colb < 66) {
        const float* at = (colb == 64) ? atts2 : attd2;
#pragma unroll
        for (int j = 0; j < 8; ++j) {
          float s2 = 0.f;
          for (int q = 0; q < 64; ++q) s2 += W2[(kb + j) * 64 + q] * at[q];
          v[j] = s2;
        }
      } else {
#pragma unroll
        for (int j = 0; j < 8; ++j) v[j] = 0.f;
      }
      Wpk2[s] = pack8bf(v);
    }
    for (int i = threadIdx.x; i < 64 * 64; i += 256) pooled[i] = 0.f;
  }
}

// ---------------- MFMA GEMM body: 64 rows x (NF*16) cols, K=128, 4 waves ----------------
// A staged as bf16 in LDS, stride 136 (granule-bank-rotating: conflict-free b128 frag reads).
// B staged per-K-phase (NF*64 uint4 live) -> LDS ~27 KB -> ~6 blocks/CU (vs 2 with full-B).
// Last col-frag = attention dots (as | ad). Other frags packed to fp8 e4m3 via lane shuffles.
template <int NF, bool ABF16>
__device__ __forceinline__ void mfma_gemm_body(int bx, const void* __restrict__ Ap,
                                               const uint4* __restrict__ Wpk,
                                               unsigned* __restrict__ Yb,
                                               float* __restrict__ as_out, float* __restrict__ ad_out) {
  __shared__ unsigned short Xs[64 * 136];
  __shared__ uint4 Ws[NF * 64];
  int t = threadIdx.x;
  int rbase = bx * 64;
  if constexpr (ABF16) {
    const uint4* A4 = (const uint4*)Ap;   // row = 128 bf16 = 16 uint4
#pragma unroll
    for (int p = 0; p < 4; ++p) {
      int i = p * 256 + t;
      int row = i >> 4, q = i & 15;
      int gr = rbase + row; if (gr > N_NODES - 1) gr = N_NODES - 1;
      *(uint4*)&Xs[row * 136 + q * 8] = A4[gr * 16 + q];
    }
  } else {
    const float4* A4 = (const float4*)Ap; // row = 32 float4
#pragma unroll
    for (int p = 0; p < 8; ++p) {
      int i = p * 256 + t;
      int row = i >> 5, q = i & 31;
      int gr = rbase + row; if (gr > N_NODES - 1) gr = N_NODES - 1;
      float4 v = A4[gr * 32 + q];
      *(uint2*)&Xs[row * 136 + q * 4] = make_uint2(pack2bf(v.x, v.y), pack2bf(v.z, v.w));
    }
  }

  int l = t & 63, wv = t >> 6;
  int lc = l & 15, lk = l >> 4;
  f32x4v acc[NF];
#pragma unroll
  for (int f = 0; f < NF; ++f) acc[f] = (f32x4v){0.f, 0.f, 0.f, 0.f};
  const unsigned short* ap = &Xs[(wv * 16 + lc) * 136 + lk * 8];
#pragma unroll
  for (int ks = 0; ks < 4; ++ks) {
    for (int i = t; i < NF * 64; i += 256) Ws[i] = Wpk[ks * NF * 64 + i];
    __syncthreads();                      // Ws(ks) ready; also covers Xs on ks==0
    bf16x8 a = *(const bf16x8*)(ap + ks * 32);
#pragma unroll
    for (int f = 0; f < NF; ++f) {
      bf16x8 b = *(const bf16x8*)&Ws[f * 64 + l];
      acc[f] = __builtin_amdgcn_mfma_f32_16x16x32_bf16(a, b, acc[f], 0, 0, 0);
    }
    if (ks < 3) __syncthreads();          // drain readers before Ws overwrite
  }

  // C/D layout: col = f*16 + (lane&15), row = (lane>>4)*4 + reg
  constexpr int NCF = NF - 1;
#pragma unroll
  for (int reg = 0; reg < 4; ++reg) {
    int row = rbase + wv * 16 + lk * 4 + reg;
    bool rok = row < N_NODES;
    float av = acc[NCF][reg];
    if (rok) {
      if constexpr (NF == 9) {
        if (lc < 4) as_out[row * 4 + lc] = av;
        else if (lc < 8) ad_out[row * 4 + lc - 4] = av;
      } else {
        if (lc == 0) as_out[row] = av;
        else if (lc == 1) ad_out[row] = av;
      }
    }
    unsigned words[NCF];
#pragma unroll
    for (int f = 0; f < NCF; ++f) {
      float v = acc[f][reg];
      float n1 = __shfl_xor(v, 1);
      unsigned pk = (unsigned)__builtin_amdgcn_cvt_pk_fp8_f32(v, n1, 0, false);  // valid on even lanes
      unsigned pk2 = (unsigned)__shfl_xor((int)pk, 2);
      words[f] = (pk & 0xffffu) | (pk2 << 16);
    }
    if (rok && (lc & 3) == 0) {
#pragma unroll
      for (int f = 0; f < NCF; ++f)
        Yb[row * (NCF * 4) + f * 4 + (lc >> 2)] = words[f];
    }
  }
}

// ---------------- dispatch 2: gemm128 (blocks 0..781) || bh partial scan (782..977) --------
__global__ __launch_bounds__(256) void gemm128_scan_kernel(
    const float* __restrict__ x, const uint4* __restrict__ Wpk1,
    unsigned* __restrict__ h1b, float* __restrict__ as1, float* __restrict__ ad1,
    const int* __restrict__ bh, int* __restrict__ bhP, int* __restrict__ blocksum) {
  if (blockIdx.x < GEMM_BLOCKS) {
    mfma_gemm_body<9, false>(blockIdx.x, x, Wpk1, h1b, as1, ad1);
  } else {
    int b = blockIdx.x - GEMM_BLOCKS;
    int g = b * 256 + threadIdx.x;
    int v = bh[g];
    int total;
    int ex = block_excl_scan(v, &total);
    bhP[g] = ex;
    if (threadIdx.x == 0) blocksum[b] = total;
  }
}

__global__ __launch_bounds__(256) void gemm64_kernel(const uint4* __restrict__ h1eb,
                                                     const uint4* __restrict__ Wpk2,
                                                     unsigned* __restrict__ h2b,
                                                     float* __restrict__ as2, float* __restrict__ ad2) {
  mfma_gemm_body<5, true>(blockIdx.x, h1eb, Wpk2, h2b, as2, ad2);
}

// ---------------- scatter (top-scan recomputed locally in LDS) ----------------
// eb entry packed u32: src (low 16 bits, N<65536) | (dst&255) << 16. Halves sort traffic.
__global__ __launch_bounds__(256) void scatter1_kernel(const int* __restrict__ ei, const int* __restrict__ bhP,
                                                       const int* __restrict__ blocksum, unsigned* __restrict__ eb) {
  __shared__ int cur[NB];
  __shared__ int boff[NB];
  int t = threadIdx.x;
  for (int i = t; i < NB; i += 256) cur[i] = 0;
  {
    int v = (t < NB) ? blocksum[t] : 0;
    int ex = block_excl_scan(v, nullptr);
    if (t < NB) boff[t] = ex;
  }
  __syncthreads();
  int start = blockIdx.x * EPB;
  for (int i = start + t; i < start + EPB; i += 256) {
    int dst = ei[N_EDGES + i];
    int src = ei[i];
    int bin = dst >> 8;
    int r = atomicAdd(&cur[bin], 1);
    int idx = bin * P1_BLOCKS + blockIdx.x;
    int pos = bhP[idx] + boff[bin] + r;
    eb[pos] = (unsigned)src | ((unsigned)(dst & 255) << 16);
  }
}

// ---------------- per-bucket fine sort -> rowptrF + col ----------------
// Bucket staged once into LDS (~16 KB avg, EBS_CAP=+16sigma; global fallback never taken).
__global__ __launch_bounds__(256) void bucket_csr_kernel(const unsigned* __restrict__ eb,
                                                         const int* __restrict__ blocksum,
                                                         int* __restrict__ rowptrF, int* __restrict__ col) {
  __shared__ unsigned ebs[EBS_CAP];
  __shared__ int cnt[256];
  __shared__ int basel[256];
  __shared__ int cur[256];
  __shared__ int sse[2];
  int b = blockIdx.x;
  int t = threadIdx.x;
  {
    int v = (t < NB) ? blocksum[t] : 0;
    int ex0 = block_excl_scan(v, nullptr);
    if (t == b) sse[0] = ex0;
    if (t == b + 1) sse[1] = ex0;
  }
  cnt[t] = 0;
  cur[t] = 0;
  __syncthreads();
  int start = sse[0];
  int end = (b == NB - 1) ? N_EDGES : sse[1];
  int m = end - start;
  bool fits = (m <= EBS_CAP);
  for (int i = t; i < m; i += 256) {
    unsigned e = eb[start + i];
    if (fits) ebs[i] = e;
    atomicAdd(&cnt[e >> 16], 1);
  }
  __syncthreads();
  int ex = block_excl_scan(cnt[t], nullptr);
  basel[t] = start + ex;
  int g = b * 256 + t;
  if (g < N_NODES) rowptrF[g] = start + ex;
  if (g == N_NODES) rowptrF[N_NODES] = N_EDGES;
  __syncthreads();
  for (int i = t; i < m; i += 256) {
    unsigned e = fits ? ebs[i] : eb[start + i];
    int d8 = e >> 16;
    int r = atomicAdd(&cur[d8], 1);
    col[basel[d8] + r] = (int)(e & 0xffffu);
  }
}

// ---------------- layer-1 gather, fused e-compute + denom; fp8 rows ----------------
__global__ __launch_bounds__(256) void agg1_kernel(const uint2* __restrict__ h1f8, const int* __restrict__ rowptr,
                                                   const int* __restrict__ col, const float* __restrict__ as1,
                                                   const float* __restrict__ ad1, const float4* __restrict__ b1v,
                                                   uint4* __restrict__ h1eb4) {
  int n = (blockIdx.x * 256 + threadIdx.x) >> 6;
  int lane = threadIdx.x & 63;
  int slot = lane >> 4;  // 0..3
  int fo = lane & 15;    // feats fo*8 .. fo*8+7
  int h = fo >> 2;       // head for these 8 feats
  int beg = rowptr[n], end = rowptr[n + 1];
  float adh = ad1[n * 4 + h];

  f32x2 acc2[4];
#pragma unroll
  for (int j = 0; j < 4; ++j) acc2[j] = (f32x2){0.f, 0.f};
  float esum = 0.f;

#define ACC_EDGE1(E)                                               \
  {                                                                \
    int src = col[E];                                              \
    float a = __expf(lrelu(as1[src * 4 + h] + adh));               \
    esum += a;                                                     \
    f32x2 av = {a, a};                                             \
    uint2 uu = h1f8[src * 16 + fo];                                \
    f32x2 p0 = __builtin_amdgcn_cvt_pk_f32_fp8(uu.x, false);       \
    f32x2 p1 = __builtin_amdgcn_cvt_pk_f32_fp8(uu.x, true);        \
    f32x2 p2 = __builtin_amdgcn_cvt_pk_f32_fp8(uu.y, false);       \
    f32x2 p3 = __builtin_amdgcn_cvt_pk_f32_fp8(uu.y, true);       \
    acc2[0] += av * p0; acc2[1] += av * p1;                        \
    acc2[2] += av * p2; acc2[3] += av * p3;                        \
  }

  int i = beg;
  for (; i + 16 <= end; i += 16) {
#pragma unroll
    for (int u = 0; u < 4; ++u) ACC_EDGE1(i + u * 4 + slot);
  }
  for (; i + 4 <= end; i += 4) ACC_EDGE1(i + slot);
  int rem = end - i;
  if (slot < rem) ACC_EDGE1(i + slot);
#undef ACC_EDGE1
  // self loop (slot 0 only)
  if (slot == 0) {
    float a = __expf(lrelu(as1[n * 4 + h] + adh));
    esum += a;
    f32x2 av = {a, a};
    uint2 uu = h1f8[n * 16 + fo];
    f32x2 p0 = __builtin_amdgcn_cvt_pk_f32_fp8(uu.x, false);
    f32x2 p1 = __builtin_amdgcn_cvt_pk_f32_fp8(uu.x, true);
    f32x2 p2 = __builtin_amdgcn_cvt_pk_f32_fp8(uu.y, false);
    f32x2 p3 = __builtin_amdgcn_cvt_pk_f32_fp8(uu.y, true);
    acc2[0] += av * p0; acc2[1] += av * p1;
    acc2[2] += av * p2; acc2[3] += av * p3;
  }
#pragma unroll
  for (int j = 0; j < 4; ++j) {
    acc2[j].x += __shfl_xor(acc2[j].x, 16);
    acc2[j].y += __shfl_xor(acc2[j].y, 16);
    acc2[j].x += __shfl_xor(acc2[j].x, 32);
    acc2[j].y += __shfl_xor(acc2[j].y, 32);
  }
  esum += __shfl_xor(esum, 16);
  esum += __shfl_xor(esum, 32);
  if (slot == 0) {
    float dsc = 1.f / esum;
    float4 b0 = b1v[fo * 2], b1 = b1v[fo * 2 + 1];
    float f0 = elu(acc2[0].x * dsc + b0.x), f1 = elu(acc2[0].y * dsc + b0.y);
    float f2 = elu(acc2[1].x * dsc + b0.z), f3 = elu(acc2[1].y * dsc + b0.w);
    float f4 = elu(acc2[2].x * dsc + b1.x), f5 = elu(acc2[2].y * dsc + b1.y);
    float f6 = elu(acc2[3].x * dsc + b1.z), f7 = elu(acc2[3].y * dsc + b1.w);
    uint4 o;
    o.x = pack2bf(f0, f1); o.y = pack2bf(f2, f3);
    o.z = pack2bf(f4, f5); o.w = pack2bf(f6, f7);
    h1eb4[n * 16 + fo] = o;  // h1e stays bf16 (feeds gemm64 MFMA A directly)
  }
}

// ---------------- layer-2 gather, fused e + denom + global add pool; fp8 rows ----------------
// NOTE: no __threadfence / last-block fusion here — per-block device-scope fences on gfx950
// trigger per-XCD L2 writeback maintenance: +220 µs across 12500 blocks (measured round 1).
__global__ __launch_bounds__(256) void agg2_kernel(const uint2* __restrict__ h2f8, const int* __restrict__ rowptr,
                                                   const int* __restrict__ col, const float* __restrict__ as2,
                                                   const float* __restrict__ ad2, const float4* __restrict__ b2v,
                                                   float* __restrict__ pooled) {
  __shared__ float red[4][64];
  int n = (blockIdx.x * 256 + threadIdx.x) >> 6;
  int lane = threadIdx.x & 63;
  int wid = threadIdx.x >> 6;
  int slot = lane >> 3;  // 0..7
  int fo = lane & 7;     // feats fo*8 .. fo*8+7
  int beg = rowptr[n], end = rowptr[n + 1];
  float ad = ad2[n];

  f32x2 acc2[4];
#pragma unroll
  for (int j = 0; j < 4; ++j) acc2[j] = (f32x2){0.f, 0.f};
  float esum = 0.f;

#define ACC_EDGE2(E)                                               \
  {                                                                \
    int src = col[E];                                              \
    float a = __expf(lrelu(as2[src] + ad));                        \
    esum += a;                                                     \
    f32x2 av = {a, a};                                             \
    uint2 uu = h2f8[src * 8 + fo];                                 \
    f32x2 p0 = __builtin_amdgcn_cvt_pk_f32_fp8(uu.x, false);       \
    f32x2 p1 = __builtin_amdgcn_cvt_pk_f32_fp8(uu.x, true);        \
    f32x2 p2 = __builtin_amdgcn_cvt_pk_f32_fp8(uu.y, false);       \
    f32x2 p3 = __builtin_amdgcn_cvt_pk_f32_fp8(uu.y, true);       \
    acc2[0] += av * p0; acc2[1] += av * p1;                        \
    acc2[2] += av * p2; acc2[3] += av * p3;                        \
  }

  int i = beg;
  for (; i + 32 <= end; i += 32) {
#pragma unroll
    for (int u = 0; u < 4; ++u) ACC_EDGE2(i + u * 8 + slot);
  }
  for (; i + 8 <= end; i += 8) ACC_EDGE2(i + slot);
  int rem = end - i;
  if (slot < rem) ACC_EDGE2(i + slot);
#undef ACC_EDGE2
  // self loop
  if (slot == 0) {
    float a = __expf(lrelu(as2[n] + ad));
    esum += a;
    f32x2 av = {a, a};
    uint2 uu = h2f8[n * 8 + fo];
    f32x2 p0 = __builtin_amdgcn_cvt_pk_f32_fp8(uu.x, false);
    f32x2 p1 = __builtin_amdgcn_cvt_pk_f32_fp8(uu.x, true);
    f32x2 p2 = __builtin_amdgcn_cvt_pk_f32_fp8(uu.y, false);
    f32x2 p3 = __builtin_amdgcn_cvt_pk_f32_fp8(uu.y, true);
    acc2[0] += av * p0; acc2[1] += av * p1;
    acc2[2] += av * p2; acc2[3] += av * p3;
  }
#pragma unroll
  for (int j = 0; j < 4; ++j) {
#pragma unroll
    for (int off = 8; off <= 32; off <<= 1) {
      acc2[j].x += __shfl_xor(acc2[j].x, off);
      acc2[j].y += __shfl_xor(acc2[j].y, off);
    }
  }
  esum += __shfl_xor(esum, 8);
  esum += __shfl_xor(esum, 16);
  esum += __shfl_xor(esum, 32);
  if (slot == 0) {
    float dsc = 1.f / esum;
    float4 b0 = b2v[fo * 2], b1 = b2v[fo * 2 + 1];
    red[wid][fo * 8 + 0] = elu(acc2[0].x * dsc + b0.x);
    red[wid][fo * 8 + 1] = elu(acc2[0].y * dsc + b0.y);
    red[wid][fo * 8 + 2] = elu(acc2[1].x * dsc + b0.z);
    red[wid][fo * 8 + 3] = elu(acc2[1].y * dsc + b0.w);
    red[wid][fo * 8 + 4] = elu(acc2[2].x * dsc + b1.x);
    red[wid][fo * 8 + 5] = elu(acc2[2].y * dsc + b1.y);
    red[wid][fo * 8 + 6] = elu(acc2[3].x * dsc + b1.z);
    red[wid][fo * 8 + 7] = elu(acc2[3].y * dsc + b1.w);
  }
  __syncthreads();
  if (threadIdx.x < 64) {
    float sum = red[0][threadIdx.x] + red[1][threadIdx.x] + red[2][threadIdx.x] + red[3][threadIdx.x];
    atomicAdd(&pooled[(blockIdx.x & 63) * 64 + threadIdx.x], sum);
  }
}

// ---------------- final: reduce pooled stripes + pooled@Wl+bl ----------------
__global__ void final_kernel(const float* __restrict__ pooledS, const float* __restrict__ Wl,
                             const float* __restrict__ bl, float* __restrict__ out) {
  __shared__ float p[64];
  int t = threadIdx.x;
  float v = 0.f;
  for (int k = 0; k < 64; ++k) v += pooledS[k * 64 + t];
  p[t] = v;
  out[t] = v;
  __syncthreads();
  if (t < 2) {
    float s = bl[t];
    for (int k = 0; k < 64; ++k) s += p[k] * Wl[k * 2 + t];
    out[64 + t] = s;
  }
}

extern "C" void kernel_launch(void* const* d_in, const int* in_sizes, int n_in,
                              void* d_out, int out_size, void* d_ws, size_t ws_size,
                              hipStream_t stream) {
  (void)in_sizes; (void)n_in; (void)out_size; (void)ws_size;
  const float* x     = (const float*)d_in[0];
  const int*   ei    = (const int*)d_in[1];
  const float* W1    = (const float*)d_in[2];
  const float* atts1 = (const float*)d_in[3];
  const float* attd1 = (const float*)d_in[4];
  const float* b1    = (const float*)d_in[5];
  const float* W2    = (const float*)d_in[6];
  const float* atts2 = (const float*)d_in[7];
  const float* attd2 = (const float*)d_in[8];
  const float* b2    = (const float*)d_in[9];
  const float* Wl    = (const float*)d_in[10];
  const float* bl    = (const float*)d_in[11];
  float* out = (float*)d_out;

  char* w = (char*)d_ws;
  unsigned* h1b  = (unsigned*)w; w += (size_t)N_NODES * 128;      // 6.4 MB fp8
  unsigned* h1eb = (unsigned*)w; w += (size_t)N_NODES * 128 * 2;  // 12.8 MB bf16
  unsigned* h2b  = (unsigned*)w; w += (size_t)N_NODES * 64;       // 3.2 MB fp8
  float* as1  = (float*)w; w += (size_t)N_NODES * 16;
  float* ad1  = (float*)w; w += (size_t)N_NODES * 16;
  float* as2  = (float*)w; w += (size_t)N_NODES * 4;
  float* ad2  = (float*)w; w += (size_t)N_NODES * 4;
  float* pooled = (float*)w; w += 64 * 64 * 4;                    // 64 stripes x 64
  uint4* Wpk1 = (uint4*)w; w += 4 * 9 * 64 * 16;                  // 36.9 KB packed bf16
  uint4* Wpk2 = (uint4*)w; w += 4 * 5 * 64 * 16;                  // 20.5 KB packed bf16
  int* rowptrF = (int*)w; w += (size_t)(N_NODES + 1) * 4 + 12;
  int* col    = (int*)w; w += (size_t)N_EDGES * 4;
  unsigned* eb = (unsigned*)w; w += (size_t)N_EDGES * 4;          // packed src|d8<<16
  int* bh     = (int*)w; w += (size_t)BH_SIZE * 4;
  int* bhP    = (int*)w; w += (size_t)BH_SIZE * 4;
  int* blocksum = (int*)w; w += 256 * 4;

  // D1: weight pack + pooled zero (2 blocks) || coarse histogram (256 blocks)
  setup_hist_kernel<<<258, 256, 0, stream>>>(ei, bh, W1, atts1, attd1, W2, atts2, attd2,
                                             Wpk1, Wpk2, pooled);
  // D2: MFMA gemm128+att (782 blocks) || bh partial scan (196 blocks)
  gemm128_scan_kernel<<<GEMM_BLOCKS + NB, 256, 0, stream>>>(x, Wpk1, h1b, as1, ad1, bh, bhP, blocksum);
  // D3: scatter into bucket order (packed u32; top-scan recomputed in LDS)
  scatter1_kernel<<<P1_BLOCKS, 256, 0, stream>>>(ei, bhP, blocksum, eb);
  // D4: per-bucket fine sort -> CSR (LDS-staged single global read)
  bucket_csr_kernel<<<NB, 256, 0, stream>>>(eb, blocksum, rowptrF, col);
  // D5: layer-1 softmax-aggregate
  agg1_kernel<<<AGG_BLOCKS, 256, 0, stream>>>((const uint2*)h1b, rowptrF, col, as1, ad1,
                                              (const float4*)b1, (uint4*)h1eb);
  // D6: MFMA gemm64+att (bf16 A direct)
  gemm64_kernel<<<GEMM_BLOCKS, 256, 0, stream>>>((const uint4*)h1eb, Wpk2, h2b, as2, ad2);
  // D7: layer-2 softmax-aggregate + pool
  agg2_kernel<<<AGG_BLOCKS, 256, 0, stream>>>((const uint2*)h2b, rowptrF, col, as2, ad2,
                                              (const float4*)b2, pooled);
  // D8: reduce stripes + final linear
  final_kernel<<<1, 64, 0, stream>>>(pooled, Wl, bl, out);
}